// Round 3
// baseline (1063.865 us; speedup 1.0000x reference)
//
#include <hip/hip_runtime.h>
#include <cstdint>

// ---------------- CSR build ----------------
// Pass A: degree count + per-edge rank (the only atomic pass).
// packed[e] = (rank << 16) | dst   (dst < 65536, rank < 65536 for this graph)

__global__ void count_rank(const int* __restrict__ dst, int* __restrict__ cnt,
                           uint32_t* __restrict__ packed, int ne) {
  int e = blockIdx.x * blockDim.x + threadIdx.x;
  if (e < ne) {
    int d = dst[e];
    int r = atomicAdd(&cnt[d], 1);
    packed[e] = ((uint32_t)r << 16) | (uint32_t)d;
  }
}

__global__ void compute_dinv(const int* __restrict__ cnt, float* __restrict__ dinv, int n) {
  int i = blockIdx.x * blockDim.x + threadIdx.x;
  if (i < n) dinv[i] = rsqrtf((float)(cnt[i] + 1));  // +1 self-loop; always > 0
}

__global__ void scan_block(const int* __restrict__ cnt, int* __restrict__ part,
                           int* __restrict__ bsum, int n) {
  __shared__ int s[1024];
  int i = blockIdx.x * 1024 + threadIdx.x;
  int v = (i < n) ? cnt[i] : 0;
  s[threadIdx.x] = v;
  __syncthreads();
  for (int off = 1; off < 1024; off <<= 1) {
    int t = (threadIdx.x >= (unsigned)off) ? s[threadIdx.x - off] : 0;
    __syncthreads();
    s[threadIdx.x] += t;
    __syncthreads();
  }
  if (i < n) part[i] = s[threadIdx.x] - v;           // exclusive within block
  if (threadIdx.x == 1023) bsum[blockIdx.x] = s[1023];
}

__global__ void scan_bsum(int* __restrict__ bsum, int nb) {  // nb <= 64
  int lane = threadIdx.x;
  int v = (lane < nb) ? bsum[lane] : 0;
  int orig = v;
  for (int off = 1; off < 64; off <<= 1) {
    int t = __shfl_up(v, off);
    if (lane >= off) v += t;
  }
  if (lane < nb) bsum[lane] = v - orig;              // exclusive block offsets
}

__global__ void finalize_rowptr(const int* __restrict__ part, const int* __restrict__ bsum,
                                int* __restrict__ row_ptr, int n, int total) {
  int i = blockIdx.x * blockDim.x + threadIdx.x;
  if (i < n) row_ptr[i] = part[i] + bsum[i >> 10];
  if (i == n) row_ptr[n] = total;
}

// Pass B: atomic-free scatter, XCD-range-localized (see R1 notes).

#define SCAT_EPB 2048  // edges per block (256 thr x 8)

__global__ __launch_bounds__(256) void scatter_csr(const int* __restrict__ src,
                                                   const uint32_t* __restrict__ packed,
                                                   const int* __restrict__ row_ptr,
                                                   int* __restrict__ col,
                                                   int ne, int nseg, int seg_size) {
  int range = blockIdx.x % nseg;
  int chunk = blockIdx.x / nseg;
  int lo = range * seg_size;
  int hi = lo + seg_size;
  int base = chunk * SCAT_EPB;
#pragma unroll
  for (int j = 0; j < 8; ++j) {
    int e = base + j * 256 + threadIdx.x;
    if (e < ne) {
      uint32_t pk = packed[e];
      int d = (int)(pk & 0xFFFFu);
      if (d >= lo && d < hi) {
        int pos = row_ptr[d] + (int)(pk >> 16);
        col[pos] = src[e];
      }
    }
  }
}

// ---------------- GEMM (fp32, 128-wide weights) fused with dinv pre-scale ----------------

__global__ __launch_bounds__(256) void gemm_scale(const float* __restrict__ in,
                                                  const float* __restrict__ W,
                                                  const float* __restrict__ dinv,
                                                  float* __restrict__ out, int nrows) {
  __shared__ float ws[16][128];
  __shared__ float xs[64][17];
  int row0 = blockIdx.x * 64;
  int tid = threadIdx.x;
  int rg = tid >> 4;   // 0..15 -> rows rg*4..rg*4+3
  int cg = tid & 15;   // 0..15 -> cols cg*4 & 64+cg*4

  float acc[4][8] = {{0.f}};

  for (int k0 = 0; k0 < 128; k0 += 16) {
    {
      int idx = tid * 8;
      int kk = idx >> 7;
      int f = idx & 127;
      float4 a = *(const float4*)&W[(size_t)(k0 + kk) * 128 + f];
      float4 b = *(const float4*)&W[(size_t)(k0 + kk) * 128 + f + 4];
      *(float4*)&ws[kk][f] = a;
      *(float4*)&ws[kk][f + 4] = b;
    }
    {
      int idx = tid * 4;
      int r = idx >> 4;
      int kk = idx & 15;
      int grow = row0 + r;
      float4 v = make_float4(0.f, 0.f, 0.f, 0.f);
      if (grow < nrows) v = *(const float4*)&in[(size_t)grow * 128 + k0 + kk];
      xs[r][kk] = v.x; xs[r][kk + 1] = v.y; xs[r][kk + 2] = v.z; xs[r][kk + 3] = v.w;
    }
    __syncthreads();
#pragma unroll
    for (int kk = 0; kk < 16; ++kk) {
      float b0[8];
      *(float4*)&b0[0] = *(const float4*)&ws[kk][cg * 4];
      *(float4*)&b0[4] = *(const float4*)&ws[kk][64 + cg * 4];
      float a0 = xs[rg * 4 + 0][kk];
      float a1 = xs[rg * 4 + 1][kk];
      float a2 = xs[rg * 4 + 2][kk];
      float a3 = xs[rg * 4 + 3][kk];
#pragma unroll
      for (int j = 0; j < 8; ++j) {
        acc[0][j] += a0 * b0[j];
        acc[1][j] += a1 * b0[j];
        acc[2][j] += a2 * b0[j];
        acc[3][j] += a3 * b0[j];
      }
    }
    __syncthreads();
  }

#pragma unroll
  for (int r = 0; r < 4; ++r) {
    int grow = row0 + rg * 4 + r;
    if (grow < nrows) {
      float s = dinv[grow];
      float4 o0 = make_float4(acc[r][0] * s, acc[r][1] * s, acc[r][2] * s, acc[r][3] * s);
      float4 o1 = make_float4(acc[r][4] * s, acc[r][5] * s, acc[r][6] * s, acc[r][7] * s);
      *(float4*)&out[(size_t)grow * 128 + cg * 4] = o0;
      *(float4*)&out[(size_t)grow * 128 + 64 + cg * 4] = o1;
    }
  }
}

// ---------------- Feature-sliced aggregation ----------------
// Slice s = blockIdx.x % 8 covers features [s*16, s*16+16) = one 64B line/row.
// With round-robin block->XCD dispatch, XCD x only touches slice x of hs
// (50000 rows x 64B = 3.2 MB -> resident in its 4 MB L2). Correctness does
// NOT depend on the mapping, only locality.
// Wave layout: 1 node/wave; lane = eo*16 + f; 4 edges processed in parallel
// (eo = 0..3), xor-shuffle reduce over edge-groups at the end.
// col/row_ptr loads are nontemporal so the 6.4 MB col stream doesn't evict
// the resident hs slice.

__global__ __launch_bounds__(256) void aggregate_sliced(const float* __restrict__ hs,
                                                        const int* __restrict__ row_ptr,
                                                        const int* __restrict__ col,
                                                        const float* __restrict__ dinv,
                                                        const float* __restrict__ bias,
                                                        float* __restrict__ out, int n) {
  int slice = blockIdx.x & 7;
  int node = (blockIdx.x >> 3) * 4 + (threadIdx.x >> 6);
  if (node >= n) return;
  int lane = threadIdx.x & 63;
  int eo = lane >> 4;       // edge-group 0..3
  int foff = slice * 16 + (lane & 15);

  int start = __builtin_nontemporal_load(&row_ptr[node]);
  int end   = __builtin_nontemporal_load(&row_ptr[node + 1]);

  float acc = (eo == 0) ? hs[(size_t)node * 128 + foff] : 0.f;  // self-loop

  for (int e = start + eo; e < end; e += 4) {
    int s = __builtin_nontemporal_load(&col[e]);
    acc += hs[(size_t)s * 128 + foff];
  }
  acc += __shfl_xor(acc, 16);
  acc += __shfl_xor(acc, 32);

  if (eo == 0) {
    float d = dinv[node];
    float v = fmaxf(acc * d + bias[foff], 0.f);
    __builtin_nontemporal_store(v, &out[(size_t)node * 128 + foff]);
  }
}

// Layer-2 variant: fuse the 16-wide partial dot with Wc; one atomicAdd per
// (node, slice) into out (pre-initialized to bc by init_out).

__global__ __launch_bounds__(256) void aggregate_dot_sliced(const float* __restrict__ hs,
                                                            const int* __restrict__ row_ptr,
                                                            const int* __restrict__ col,
                                                            const float* __restrict__ dinv,
                                                            const float* __restrict__ bias,
                                                            const float* __restrict__ Wc,
                                                            float* __restrict__ out, int n) {
  int slice = blockIdx.x & 7;
  int node = (blockIdx.x >> 3) * 4 + (threadIdx.x >> 6);
  if (node >= n) return;
  int lane = threadIdx.x & 63;
  int eo = lane >> 4;
  int foff = slice * 16 + (lane & 15);

  int start = __builtin_nontemporal_load(&row_ptr[node]);
  int end   = __builtin_nontemporal_load(&row_ptr[node + 1]);

  float acc = (eo == 0) ? hs[(size_t)node * 128 + foff] : 0.f;  // self-loop

  for (int e = start + eo; e < end; e += 4) {
    int s = __builtin_nontemporal_load(&col[e]);
    acc += hs[(size_t)s * 128 + foff];
  }
  acc += __shfl_xor(acc, 16);
  acc += __shfl_xor(acc, 32);

  // all lanes now hold the slice-sum for their feature; compute partial dot
  float d = dinv[node];
  float v = fmaxf(acc * d + bias[foff], 0.f);
  float partial = v * Wc[foff];
  partial += __shfl_xor(partial, 1);
  partial += __shfl_xor(partial, 2);
  partial += __shfl_xor(partial, 4);
  partial += __shfl_xor(partial, 8);
  if (lane == 0) atomicAdd(&out[node], partial);
}

__global__ void init_out(float* __restrict__ out, const float* __restrict__ bc, int n) {
  int i = blockIdx.x * blockDim.x + threadIdx.x;
  if (i < n) out[i] = bc[0];
}

// ---------------- launch ----------------

extern "C" void kernel_launch(void* const* d_in, const int* in_sizes, int n_in,
                              void* d_out, int out_size, void* d_ws, size_t ws_size,
                              hipStream_t stream) {
  const float* x  = (const float*)d_in[0];
  const int* ei   = (const int*)d_in[1];
  const float* W1 = (const float*)d_in[2];
  const float* b1 = (const float*)d_in[3];
  const float* W2 = (const float*)d_in[4];
  const float* b2 = (const float*)d_in[5];
  const float* Wc = (const float*)d_in[6];
  const float* bc = (const float*)d_in[7];
  float* out = (float*)d_out;

  int n  = in_sizes[0] / 128;
  int ne = in_sizes[1] / 2;
  const int* src = ei;
  const int* dst = ei + ne;

  char* p = (char*)d_ws;
  auto alloc = [&](size_t bytes) {
    char* r = p;
    p += (bytes + 255) & ~(size_t)255;
    return r;
  };
  int*   cnt     = (int*)alloc((size_t)n * 4);
  int*   part    = (int*)alloc((size_t)n * 4);
  int*   bsum    = (int*)alloc(64 * 4);
  int*   row_ptr = (int*)alloc((size_t)(n + 1) * 4);
  float* dinv    = (float*)alloc((size_t)n * 4);
  int*   col     = (int*)alloc((size_t)ne * 4);
  float* hs      = (float*)alloc((size_t)n * 128 * 4);
  float* hbuf    = (float*)alloc((size_t)n * 128 * 4);
  // packed aliases hbuf: packed is dead after scatter_csr; hbuf first written
  // by aggregate_sliced (layer 1), which runs strictly later on the stream.
  uint32_t* packed = (uint32_t*)hbuf;

  hipMemsetAsync(cnt, 0, (size_t)n * 4, stream);
  count_rank<<<(ne + 255) / 256, 256, 0, stream>>>(dst, cnt, packed, ne);
  compute_dinv<<<(n + 255) / 256, 256, 0, stream>>>(cnt, dinv, n);
  int nsb = (n + 1023) / 1024;  // 49 for n=50000, must be <= 64
  scan_block<<<nsb, 1024, 0, stream>>>(cnt, part, bsum, n);
  scan_bsum<<<1, 64, 0, stream>>>(bsum, nsb);
  finalize_rowptr<<<(n + 1 + 255) / 256, 256, 0, stream>>>(part, bsum, row_ptr, n, ne);

  const int NSEG = 8;
  int seg_size = (n + NSEG - 1) / NSEG;
  int nchunks = (ne + SCAT_EPB - 1) / SCAT_EPB;
  scatter_csr<<<nchunks * NSEG, 256, 0, stream>>>(src, packed, row_ptr, col, ne, NSEG, seg_size);

  int gemm_blocks = (n + 63) / 64;
  int agg_blocks = ((n + 3) / 4) * 8;  // 4 nodes/block x 8 feature slices

  gemm_scale<<<gemm_blocks, 256, 0, stream>>>(x, W1, dinv, hs, n);
  aggregate_sliced<<<agg_blocks, 256, 0, stream>>>(hs, row_ptr, col, dinv, b1, hbuf, n);
  gemm_scale<<<gemm_blocks, 256, 0, stream>>>(hbuf, W2, dinv, hs, n);
  init_out<<<(n + 255) / 256, 256, 0, stream>>>(out, bc, n);
  aggregate_dot_sliced<<<agg_blocks, 256, 0, stream>>>(hs, row_ptr, col, dinv, b2, Wc, out, n);
}

// Round 4
// 379.234 us; speedup vs baseline: 2.8053x; 2.8053x over previous
//
#include <hip/hip_runtime.h>
#include <cstdint>

// ---------------- CSR build ----------------
// Pass A: degree count + per-edge rank (the only atomic pass).
// packed[e] = (rank << 16) | dst   (dst < 65536, rank < 65536 for this graph)

__global__ void count_rank(const int* __restrict__ dst, int* __restrict__ cnt,
                           uint32_t* __restrict__ packed, int ne) {
  int e = blockIdx.x * blockDim.x + threadIdx.x;
  if (e < ne) {
    int d = dst[e];
    int r = atomicAdd(&cnt[d], 1);
    packed[e] = ((uint32_t)r << 16) | (uint32_t)d;
  }
}

__global__ void compute_dinv(const int* __restrict__ cnt, float* __restrict__ dinv, int n) {
  int i = blockIdx.x * blockDim.x + threadIdx.x;
  if (i < n) dinv[i] = rsqrtf((float)(cnt[i] + 1));  // +1 self-loop; always > 0
}

__global__ void scan_block(const int* __restrict__ cnt, int* __restrict__ part,
                           int* __restrict__ bsum, int n) {
  __shared__ int s[1024];
  int i = blockIdx.x * 1024 + threadIdx.x;
  int v = (i < n) ? cnt[i] : 0;
  s[threadIdx.x] = v;
  __syncthreads();
  for (int off = 1; off < 1024; off <<= 1) {
    int t = (threadIdx.x >= (unsigned)off) ? s[threadIdx.x - off] : 0;
    __syncthreads();
    s[threadIdx.x] += t;
    __syncthreads();
  }
  if (i < n) part[i] = s[threadIdx.x] - v;           // exclusive within block
  if (threadIdx.x == 1023) bsum[blockIdx.x] = s[1023];
}

__global__ void scan_bsum(int* __restrict__ bsum, int nb) {  // nb <= 64
  int lane = threadIdx.x;
  int v = (lane < nb) ? bsum[lane] : 0;
  int orig = v;
  for (int off = 1; off < 64; off <<= 1) {
    int t = __shfl_up(v, off);
    if (lane >= off) v += t;
  }
  if (lane < nb) bsum[lane] = v - orig;              // exclusive block offsets
}

__global__ void finalize_rowptr(const int* __restrict__ part, const int* __restrict__ bsum,
                                int* __restrict__ row_ptr, int n, int total) {
  int i = blockIdx.x * blockDim.x + threadIdx.x;
  if (i < n) row_ptr[i] = part[i] + bsum[i >> 10];
  if (i == n) row_ptr[n] = total;
}

// Pass B: atomic-free scatter, XCD-range-localized (see R1 notes; WRITE_SIZE
// dropped 101 MB -> ~10 MB with this structure).

#define SCAT_EPB 2048  // edges per block (256 thr x 8)

__global__ __launch_bounds__(256) void scatter_csr(const int* __restrict__ src,
                                                   const uint32_t* __restrict__ packed,
                                                   const int* __restrict__ row_ptr,
                                                   int* __restrict__ col,
                                                   int ne, int nseg, int seg_size) {
  int range = blockIdx.x % nseg;
  int chunk = blockIdx.x / nseg;
  int lo = range * seg_size;
  int hi = lo + seg_size;
  int base = chunk * SCAT_EPB;
#pragma unroll
  for (int j = 0; j < 8; ++j) {
    int e = base + j * 256 + threadIdx.x;
    if (e < ne) {
      uint32_t pk = packed[e];
      int d = (int)(pk & 0xFFFFu);
      if (d >= lo && d < hi) {
        int pos = row_ptr[d] + (int)(pk >> 16);
        col[pos] = src[e];
      }
    }
  }
}

// ---------------- GEMM (fp32, 128-wide weights) fused with dinv pre-scale ----------------

__global__ __launch_bounds__(256) void gemm_scale(const float* __restrict__ in,
                                                  const float* __restrict__ W,
                                                  const float* __restrict__ dinv,
                                                  float* __restrict__ out, int nrows) {
  __shared__ float ws[16][128];
  __shared__ float xs[64][17];
  int row0 = blockIdx.x * 64;
  int tid = threadIdx.x;
  int rg = tid >> 4;   // 0..15 -> rows rg*4..rg*4+3
  int cg = tid & 15;   // 0..15 -> cols cg*4 & 64+cg*4

  float acc[4][8] = {{0.f}};

  for (int k0 = 0; k0 < 128; k0 += 16) {
    {
      int idx = tid * 8;
      int kk = idx >> 7;
      int f = idx & 127;
      float4 a = *(const float4*)&W[(size_t)(k0 + kk) * 128 + f];
      float4 b = *(const float4*)&W[(size_t)(k0 + kk) * 128 + f + 4];
      *(float4*)&ws[kk][f] = a;
      *(float4*)&ws[kk][f + 4] = b;
    }
    {
      int idx = tid * 4;
      int r = idx >> 4;
      int kk = idx & 15;
      int grow = row0 + r;
      float4 v = make_float4(0.f, 0.f, 0.f, 0.f);
      if (grow < nrows) v = *(const float4*)&in[(size_t)grow * 128 + k0 + kk];
      xs[r][kk] = v.x; xs[r][kk + 1] = v.y; xs[r][kk + 2] = v.z; xs[r][kk + 3] = v.w;
    }
    __syncthreads();
#pragma unroll
    for (int kk = 0; kk < 16; ++kk) {
      float b0[8];
      *(float4*)&b0[0] = *(const float4*)&ws[kk][cg * 4];
      *(float4*)&b0[4] = *(const float4*)&ws[kk][64 + cg * 4];
      float a0 = xs[rg * 4 + 0][kk];
      float a1 = xs[rg * 4 + 1][kk];
      float a2 = xs[rg * 4 + 2][kk];
      float a3 = xs[rg * 4 + 3][kk];
#pragma unroll
      for (int j = 0; j < 8; ++j) {
        acc[0][j] += a0 * b0[j];
        acc[1][j] += a1 * b0[j];
        acc[2][j] += a2 * b0[j];
        acc[3][j] += a3 * b0[j];
      }
    }
    __syncthreads();
  }

#pragma unroll
  for (int r = 0; r < 4; ++r) {
    int grow = row0 + rg * 4 + r;
    if (grow < nrows) {
      float s = dinv[grow];
      float4 o0 = make_float4(acc[r][0] * s, acc[r][1] * s, acc[r][2] * s, acc[r][3] * s);
      float4 o1 = make_float4(acc[r][4] * s, acc[r][5] * s, acc[r][6] * s, acc[r][7] * s);
      *(float4*)&out[(size_t)grow * 128 + cg * 4] = o0;
      *(float4*)&out[(size_t)grow * 128 + 64 + cg * 4] = o1;
    }
  }
}

// ---------------- Aggregation: 1 node/wave, half-wave = full 512B row ----------------
// lane = half*32 + f4; f4 indexes float4 (32 x 16B = full 128-feature row).
// Half h processes edges start+h, start+h+2, ... ; unroll x4 -> 8 edges /
// 4 KB outstanding per wave (R3 lesson: maximize bytes in flight for random
// gathers). Merge halves with 4 component shuffles at the end.

__global__ __launch_bounds__(256) void aggregate(const float* __restrict__ hs,
                                                 const int* __restrict__ row_ptr,
                                                 const int* __restrict__ col,
                                                 const float* __restrict__ dinv,
                                                 const float* __restrict__ bias,
                                                 float* __restrict__ out, int n) {
  int node = (blockIdx.x * blockDim.x + threadIdx.x) >> 6;
  if (node >= n) return;
  int lane = threadIdx.x & 63;
  int half = lane >> 5;
  int f4 = lane & 31;
  const float4* hs4 = (const float4*)hs;  // row stride = 32 float4

  int start = row_ptr[node];
  int end = row_ptr[node + 1];

  float4 acc = make_float4(0.f, 0.f, 0.f, 0.f);
  if (half == 0) acc = hs4[(size_t)node * 32 + f4];  // self-loop

  int e = start + half;
  for (; e + 6 < end; e += 8) {
    int s0 = col[e + 0];
    int s1 = col[e + 2];
    int s2 = col[e + 4];
    int s3 = col[e + 6];
    float4 v0 = hs4[(size_t)s0 * 32 + f4];
    float4 v1 = hs4[(size_t)s1 * 32 + f4];
    float4 v2 = hs4[(size_t)s2 * 32 + f4];
    float4 v3 = hs4[(size_t)s3 * 32 + f4];
    acc.x += (v0.x + v1.x) + (v2.x + v3.x);
    acc.y += (v0.y + v1.y) + (v2.y + v3.y);
    acc.z += (v0.z + v1.z) + (v2.z + v3.z);
    acc.w += (v0.w + v1.w) + (v2.w + v3.w);
  }
  for (; e < end; e += 2) {
    float4 v = hs4[(size_t)col[e] * 32 + f4];
    acc.x += v.x; acc.y += v.y; acc.z += v.z; acc.w += v.w;
  }

  acc.x += __shfl_xor(acc.x, 32);
  acc.y += __shfl_xor(acc.y, 32);
  acc.z += __shfl_xor(acc.z, 32);
  acc.w += __shfl_xor(acc.w, 32);

  if (half == 0) {
    float d = dinv[node];
    float4 b = ((const float4*)bias)[f4];
    float4 o;
    o.x = fmaxf(acc.x * d + b.x, 0.f);
    o.y = fmaxf(acc.y * d + b.y, 0.f);
    o.z = fmaxf(acc.z * d + b.z, 0.f);
    o.w = fmaxf(acc.w * d + b.w, 0.f);
    ((float4*)out)[(size_t)node * 32 + f4] = o;
  }
}

// Layer-2 variant: same gather, fused 128->1 projection. Full row lives in
// one wave -> plain shuffle reduce, no atomics, no init pass.

__global__ __launch_bounds__(256) void aggregate_dot(const float* __restrict__ hs,
                                                     const int* __restrict__ row_ptr,
                                                     const int* __restrict__ col,
                                                     const float* __restrict__ dinv,
                                                     const float* __restrict__ bias,
                                                     const float* __restrict__ Wc,
                                                     const float* __restrict__ bc,
                                                     float* __restrict__ out, int n) {
  int node = (blockIdx.x * blockDim.x + threadIdx.x) >> 6;
  if (node >= n) return;
  int lane = threadIdx.x & 63;
  int half = lane >> 5;
  int f4 = lane & 31;
  const float4* hs4 = (const float4*)hs;

  int start = row_ptr[node];
  int end = row_ptr[node + 1];

  float4 acc = make_float4(0.f, 0.f, 0.f, 0.f);
  if (half == 0) acc = hs4[(size_t)node * 32 + f4];  // self-loop

  int e = start + half;
  for (; e + 6 < end; e += 8) {
    int s0 = col[e + 0];
    int s1 = col[e + 2];
    int s2 = col[e + 4];
    int s3 = col[e + 6];
    float4 v0 = hs4[(size_t)s0 * 32 + f4];
    float4 v1 = hs4[(size_t)s1 * 32 + f4];
    float4 v2 = hs4[(size_t)s2 * 32 + f4];
    float4 v3 = hs4[(size_t)s3 * 32 + f4];
    acc.x += (v0.x + v1.x) + (v2.x + v3.x);
    acc.y += (v0.y + v1.y) + (v2.y + v3.y);
    acc.z += (v0.z + v1.z) + (v2.z + v3.z);
    acc.w += (v0.w + v1.w) + (v2.w + v3.w);
  }
  for (; e < end; e += 2) {
    float4 v = hs4[(size_t)col[e] * 32 + f4];
    acc.x += v.x; acc.y += v.y; acc.z += v.z; acc.w += v.w;
  }

  acc.x += __shfl_xor(acc.x, 32);
  acc.y += __shfl_xor(acc.y, 32);
  acc.z += __shfl_xor(acc.z, 32);
  acc.w += __shfl_xor(acc.w, 32);

  float d = dinv[node];
  float4 b = ((const float4*)bias)[f4];
  float4 w = ((const float4*)Wc)[f4];
  float s = fmaxf(acc.x * d + b.x, 0.f) * w.x
          + fmaxf(acc.y * d + b.y, 0.f) * w.y
          + fmaxf(acc.z * d + b.z, 0.f) * w.z
          + fmaxf(acc.w * d + b.w, 0.f) * w.w;
#pragma unroll
  for (int off = 16; off; off >>= 1) s += __shfl_xor(s, off);
  if (lane == 0) out[node] = s + bc[0];
}

// ---------------- launch ----------------

extern "C" void kernel_launch(void* const* d_in, const int* in_sizes, int n_in,
                              void* d_out, int out_size, void* d_ws, size_t ws_size,
                              hipStream_t stream) {
  const float* x  = (const float*)d_in[0];
  const int* ei   = (const int*)d_in[1];
  const float* W1 = (const float*)d_in[2];
  const float* b1 = (const float*)d_in[3];
  const float* W2 = (const float*)d_in[4];
  const float* b2 = (const float*)d_in[5];
  const float* Wc = (const float*)d_in[6];
  const float* bc = (const float*)d_in[7];
  float* out = (float*)d_out;

  int n  = in_sizes[0] / 128;
  int ne = in_sizes[1] / 2;
  const int* src = ei;
  const int* dst = ei + ne;

  char* p = (char*)d_ws;
  auto alloc = [&](size_t bytes) {
    char* r = p;
    p += (bytes + 255) & ~(size_t)255;
    return r;
  };
  int*   cnt     = (int*)alloc((size_t)n * 4);
  int*   part    = (int*)alloc((size_t)n * 4);
  int*   bsum    = (int*)alloc(64 * 4);
  int*   row_ptr = (int*)alloc((size_t)(n + 1) * 4);
  float* dinv    = (float*)alloc((size_t)n * 4);
  int*   col     = (int*)alloc((size_t)ne * 4);
  float* hs      = (float*)alloc((size_t)n * 128 * 4);
  float* hbuf    = (float*)alloc((size_t)n * 128 * 4);
  // packed aliases hbuf: packed is dead after scatter_csr; hbuf first written
  // by aggregate (layer 1), which runs strictly later on the stream.
  uint32_t* packed = (uint32_t*)hbuf;

  hipMemsetAsync(cnt, 0, (size_t)n * 4, stream);
  count_rank<<<(ne + 255) / 256, 256, 0, stream>>>(dst, cnt, packed, ne);
  compute_dinv<<<(n + 255) / 256, 256, 0, stream>>>(cnt, dinv, n);
  int nsb = (n + 1023) / 1024;  // 49 for n=50000, must be <= 64
  scan_block<<<nsb, 1024, 0, stream>>>(cnt, part, bsum, n);
  scan_bsum<<<1, 64, 0, stream>>>(bsum, nsb);
  finalize_rowptr<<<(n + 1 + 255) / 256, 256, 0, stream>>>(part, bsum, row_ptr, n, ne);

  const int NSEG = 8;
  int seg_size = (n + NSEG - 1) / NSEG;
  int nchunks = (ne + SCAT_EPB - 1) / SCAT_EPB;
  scatter_csr<<<nchunks * NSEG, 256, 0, stream>>>(src, packed, row_ptr, col, ne, NSEG, seg_size);

  int gemm_blocks = (n + 63) / 64;
  int agg_blocks = (n + 3) / 4;  // 4 waves/block, 1 wave/node

  gemm_scale<<<gemm_blocks, 256, 0, stream>>>(x, W1, dinv, hs, n);
  aggregate<<<agg_blocks, 256, 0, stream>>>(hs, row_ptr, col, dinv, b1, hbuf, n);
  gemm_scale<<<gemm_blocks, 256, 0, stream>>>(hbuf, W2, dinv, hs, n);
  aggregate_dot<<<agg_blocks, 256, 0, stream>>>(hs, row_ptr, col, dinv, b2, Wc, bc, out, n);
}

// Round 5
// 283.180 us; speedup vs baseline: 3.7568x; 1.3392x over previous
//
#include <hip/hip_runtime.h>
#include <hip/hip_fp16.h>
#include <cstdint>

// ---------------- CSR build ----------------
// Pass A: degree count + per-edge rank (the only atomic pass).
// packed[e] = (rank << 16) | dst   (dst < 65536, rank < 65536 for this graph)

__global__ void count_rank(const int* __restrict__ dst, int* __restrict__ cnt,
                           uint32_t* __restrict__ packed, int ne) {
  int e = blockIdx.x * blockDim.x + threadIdx.x;
  if (e < ne) {
    int d = dst[e];
    int r = atomicAdd(&cnt[d], 1);
    packed[e] = ((uint32_t)r << 16) | (uint32_t)d;
  }
}

__global__ void compute_dinv(const int* __restrict__ cnt, float* __restrict__ dinv, int n) {
  int i = blockIdx.x * blockDim.x + threadIdx.x;
  if (i < n) dinv[i] = rsqrtf((float)(cnt[i] + 1));  // +1 self-loop; always > 0
}

__global__ void scan_block(const int* __restrict__ cnt, int* __restrict__ part,
                           int* __restrict__ bsum, int n) {
  __shared__ int s[1024];
  int i = blockIdx.x * 1024 + threadIdx.x;
  int v = (i < n) ? cnt[i] : 0;
  s[threadIdx.x] = v;
  __syncthreads();
  for (int off = 1; off < 1024; off <<= 1) {
    int t = (threadIdx.x >= (unsigned)off) ? s[threadIdx.x - off] : 0;
    __syncthreads();
    s[threadIdx.x] += t;
    __syncthreads();
  }
  if (i < n) part[i] = s[threadIdx.x] - v;           // exclusive within block
  if (threadIdx.x == 1023) bsum[blockIdx.x] = s[1023];
}

__global__ void scan_bsum(int* __restrict__ bsum, int nb) {  // nb <= 64
  int lane = threadIdx.x;
  int v = (lane < nb) ? bsum[lane] : 0;
  int orig = v;
  for (int off = 1; off < 64; off <<= 1) {
    int t = __shfl_up(v, off);
    if (lane >= off) v += t;
  }
  if (lane < nb) bsum[lane] = v - orig;              // exclusive block offsets
}

__global__ void finalize_rowptr(const int* __restrict__ part, const int* __restrict__ bsum,
                                int* __restrict__ row_ptr, int n, int total) {
  int i = blockIdx.x * blockDim.x + threadIdx.x;
  if (i < n) row_ptr[i] = part[i] + bsum[i >> 10];
  if (i == n) row_ptr[n] = total;
}

// Pass B: atomic-free scatter, XCD-range-localized (R1: WRITE_SIZE 101->10 MB).

#define SCAT_EPB 2048  // edges per block (256 thr x 8)

__global__ __launch_bounds__(256) void scatter_csr(const int* __restrict__ src,
                                                   const uint32_t* __restrict__ packed,
                                                   const int* __restrict__ row_ptr,
                                                   int* __restrict__ col,
                                                   int ne, int nseg, int seg_size) {
  int range = blockIdx.x % nseg;
  int chunk = blockIdx.x / nseg;
  int lo = range * seg_size;
  int hi = lo + seg_size;
  int base = chunk * SCAT_EPB;
#pragma unroll
  for (int j = 0; j < 8; ++j) {
    int e = base + j * 256 + threadIdx.x;
    if (e < ne) {
      uint32_t pk = packed[e];
      int d = (int)(pk & 0xFFFFu);
      if (d >= lo && d < hi) {
        int pos = row_ptr[d] + (int)(pk >> 16);
        col[pos] = src[e];
      }
    }
  }
}

// ---------------- GEMM (fp32 in, fp16 out) fused with dinv pre-scale ----------------
// R5: epilogue converts to fp16 — halves the aggregate's gather bytes
// (the aggregate is fabric-BW bound at ~3.8 TB/s on 357 MB; see R4 notes).

__global__ __launch_bounds__(256) void gemm_scale_h(const float* __restrict__ in,
                                                    const float* __restrict__ W,
                                                    const float* __restrict__ dinv,
                                                    __half* __restrict__ out, int nrows) {
  __shared__ float ws[16][128];
  __shared__ float xs[64][17];
  int row0 = blockIdx.x * 64;
  int tid = threadIdx.x;
  int rg = tid >> 4;   // 0..15 -> rows rg*4..rg*4+3
  int cg = tid & 15;   // 0..15 -> cols cg*4 & 64+cg*4

  float acc[4][8] = {{0.f}};

  for (int k0 = 0; k0 < 128; k0 += 16) {
    {
      int idx = tid * 8;
      int kk = idx >> 7;
      int f = idx & 127;
      float4 a = *(const float4*)&W[(size_t)(k0 + kk) * 128 + f];
      float4 b = *(const float4*)&W[(size_t)(k0 + kk) * 128 + f + 4];
      *(float4*)&ws[kk][f] = a;
      *(float4*)&ws[kk][f + 4] = b;
    }
    {
      int idx = tid * 4;
      int r = idx >> 4;
      int kk = idx & 15;
      int grow = row0 + r;
      float4 v = make_float4(0.f, 0.f, 0.f, 0.f);
      if (grow < nrows) v = *(const float4*)&in[(size_t)grow * 128 + k0 + kk];
      xs[r][kk] = v.x; xs[r][kk + 1] = v.y; xs[r][kk + 2] = v.z; xs[r][kk + 3] = v.w;
    }
    __syncthreads();
#pragma unroll
    for (int kk = 0; kk < 16; ++kk) {
      float b0[8];
      *(float4*)&b0[0] = *(const float4*)&ws[kk][cg * 4];
      *(float4*)&b0[4] = *(const float4*)&ws[kk][64 + cg * 4];
      float a0 = xs[rg * 4 + 0][kk];
      float a1 = xs[rg * 4 + 1][kk];
      float a2 = xs[rg * 4 + 2][kk];
      float a3 = xs[rg * 4 + 3][kk];
#pragma unroll
      for (int j = 0; j < 8; ++j) {
        acc[0][j] += a0 * b0[j];
        acc[1][j] += a1 * b0[j];
        acc[2][j] += a2 * b0[j];
        acc[3][j] += a3 * b0[j];
      }
    }
    __syncthreads();
  }

#pragma unroll
  for (int r = 0; r < 4; ++r) {
    int grow = row0 + rg * 4 + r;
    if (grow < nrows) {
      float s = dinv[grow];
      __half h[8];
#pragma unroll
      for (int j = 0; j < 8; ++j) h[j] = __float2half_rn(acc[r][j] * s);
      *(uint2*)&out[(size_t)grow * 128 + cg * 4] = *(uint2*)&h[0];
      *(uint2*)&out[(size_t)grow * 128 + 64 + cg * 4] = *(uint2*)&h[4];
    }
  }
}

// ---------------- fp16 row gather helpers ----------------

__device__ inline float4 h4_to_f4(uint2 u) {
  __half2 a = *(__half2*)&u.x;
  __half2 b = *(__half2*)&u.y;
  float2 fa = __half22float2(a);
  float2 fb = __half22float2(b);
  return make_float4(fa.x, fa.y, fb.x, fb.y);
}

// ---------------- Aggregation: 1 node/wave, half-wave = full 256B fp16 row ----------------
// lane = half*32 + f4; f4 indexes uint2 (4 halves). Half h walks edges
// start+h, start+h+2, ...; unrolled x8 -> 16 edges / 4 KB outstanding per
// wave. Accumulation in fp32. Merge halves via 4 component shuffles.

__global__ __launch_bounds__(256) void aggregate_h(const __half* __restrict__ hsh,
                                                   const int* __restrict__ row_ptr,
                                                   const int* __restrict__ col,
                                                   const float* __restrict__ dinv,
                                                   const float* __restrict__ bias,
                                                   float* __restrict__ out, int n) {
  int node = (blockIdx.x * blockDim.x + threadIdx.x) >> 6;
  if (node >= n) return;
  int lane = threadIdx.x & 63;
  int half_ = lane >> 5;
  int f4 = lane & 31;
  const uint2* rows = (const uint2*)hsh;  // row stride = 32 uint2

  int start = row_ptr[node];
  int end = row_ptr[node + 1];

  float4 acc = make_float4(0.f, 0.f, 0.f, 0.f);
  if (half_ == 0) acc = h4_to_f4(rows[(size_t)node * 32 + f4]);  // self-loop

  int e = start + half_;
  for (; e + 14 < end; e += 16) {
    uint2 u[8];
#pragma unroll
    for (int j = 0; j < 8; ++j) u[j] = rows[(size_t)col[e + 2 * j] * 32 + f4];
#pragma unroll
    for (int j = 0; j < 8; ++j) {
      float4 v = h4_to_f4(u[j]);
      acc.x += v.x; acc.y += v.y; acc.z += v.z; acc.w += v.w;
    }
  }
  for (; e < end; e += 2) {
    float4 v = h4_to_f4(rows[(size_t)col[e] * 32 + f4]);
    acc.x += v.x; acc.y += v.y; acc.z += v.z; acc.w += v.w;
  }

  acc.x += __shfl_xor(acc.x, 32);
  acc.y += __shfl_xor(acc.y, 32);
  acc.z += __shfl_xor(acc.z, 32);
  acc.w += __shfl_xor(acc.w, 32);

  if (half_ == 0) {
    float d = dinv[node];
    float4 b = ((const float4*)bias)[f4];
    float4 o;
    o.x = fmaxf(acc.x * d + b.x, 0.f);
    o.y = fmaxf(acc.y * d + b.y, 0.f);
    o.z = fmaxf(acc.z * d + b.z, 0.f);
    o.w = fmaxf(acc.w * d + b.w, 0.f);
    ((float4*)out)[(size_t)node * 32 + f4] = o;
  }
}

// Layer-2 variant: same gather, fused 128->1 projection with Wc.

__global__ __launch_bounds__(256) void aggregate_dot_h(const __half* __restrict__ hsh,
                                                       const int* __restrict__ row_ptr,
                                                       const int* __restrict__ col,
                                                       const float* __restrict__ dinv,
                                                       const float* __restrict__ bias,
                                                       const float* __restrict__ Wc,
                                                       const float* __restrict__ bc,
                                                       float* __restrict__ out, int n) {
  int node = (blockIdx.x * blockDim.x + threadIdx.x) >> 6;
  if (node >= n) return;
  int lane = threadIdx.x & 63;
  int half_ = lane >> 5;
  int f4 = lane & 31;
  const uint2* rows = (const uint2*)hsh;

  int start = row_ptr[node];
  int end = row_ptr[node + 1];

  float4 acc = make_float4(0.f, 0.f, 0.f, 0.f);
  if (half_ == 0) acc = h4_to_f4(rows[(size_t)node * 32 + f4]);  // self-loop

  int e = start + half_;
  for (; e + 14 < end; e += 16) {
    uint2 u[8];
#pragma unroll
    for (int j = 0; j < 8; ++j) u[j] = rows[(size_t)col[e + 2 * j] * 32 + f4];
#pragma unroll
    for (int j = 0; j < 8; ++j) {
      float4 v = h4_to_f4(u[j]);
      acc.x += v.x; acc.y += v.y; acc.z += v.z; acc.w += v.w;
    }
  }
  for (; e < end; e += 2) {
    float4 v = h4_to_f4(rows[(size_t)col[e] * 32 + f4]);
    acc.x += v.x; acc.y += v.y; acc.z += v.z; acc.w += v.w;
  }

  acc.x += __shfl_xor(acc.x, 32);
  acc.y += __shfl_xor(acc.y, 32);
  acc.z += __shfl_xor(acc.z, 32);
  acc.w += __shfl_xor(acc.w, 32);

  float d = dinv[node];
  float4 b = ((const float4*)bias)[f4];
  float4 w = ((const float4*)Wc)[f4];
  float s = fmaxf(acc.x * d + b.x, 0.f) * w.x
          + fmaxf(acc.y * d + b.y, 0.f) * w.y
          + fmaxf(acc.z * d + b.z, 0.f) * w.z
          + fmaxf(acc.w * d + b.w, 0.f) * w.w;
#pragma unroll
  for (int off = 16; off; off >>= 1) s += __shfl_xor(s, off);
  if (lane == 0) out[node] = s + bc[0];
}

// ---------------- launch ----------------

extern "C" void kernel_launch(void* const* d_in, const int* in_sizes, int n_in,
                              void* d_out, int out_size, void* d_ws, size_t ws_size,
                              hipStream_t stream) {
  const float* x  = (const float*)d_in[0];
  const int* ei   = (const int*)d_in[1];
  const float* W1 = (const float*)d_in[2];
  const float* b1 = (const float*)d_in[3];
  const float* W2 = (const float*)d_in[4];
  const float* b2 = (const float*)d_in[5];
  const float* Wc = (const float*)d_in[6];
  const float* bc = (const float*)d_in[7];
  float* out = (float*)d_out;

  int n  = in_sizes[0] / 128;
  int ne = in_sizes[1] / 2;
  const int* src = ei;
  const int* dst = ei + ne;

  char* p = (char*)d_ws;
  auto alloc = [&](size_t bytes) {
    char* r = p;
    p += (bytes + 255) & ~(size_t)255;
    return r;
  };
  int*    cnt     = (int*)alloc((size_t)n * 4);
  int*    part    = (int*)alloc((size_t)n * 4);
  int*    bsum    = (int*)alloc(64 * 4);
  int*    row_ptr = (int*)alloc((size_t)(n + 1) * 4);
  float*  dinv    = (float*)alloc((size_t)n * 4);
  int*    col     = (int*)alloc((size_t)ne * 4);
  __half* hsh     = (__half*)alloc((size_t)n * 128 * 2);  // fp16 GEMM output
  float*  h1      = (float*)alloc((size_t)n * 128 * 4);   // fp32 layer-1 output
  // packed aliases h1: packed is dead after scatter_csr; h1 first written by
  // aggregate_h (layer 1), which runs strictly later on the stream.
  uint32_t* packed = (uint32_t*)h1;

  hipMemsetAsync(cnt, 0, (size_t)n * 4, stream);
  count_rank<<<(ne + 255) / 256, 256, 0, stream>>>(dst, cnt, packed, ne);
  compute_dinv<<<(n + 255) / 256, 256, 0, stream>>>(cnt, dinv, n);
  int nsb = (n + 1023) / 1024;  // 49 for n=50000, must be <= 64
  scan_block<<<nsb, 1024, 0, stream>>>(cnt, part, bsum, n);
  scan_bsum<<<1, 64, 0, stream>>>(bsum, nsb);
  finalize_rowptr<<<(n + 1 + 255) / 256, 256, 0, stream>>>(part, bsum, row_ptr, n, ne);

  const int NSEG = 8;
  int seg_size = (n + NSEG - 1) / NSEG;
  int nchunks = (ne + SCAT_EPB - 1) / SCAT_EPB;
  scatter_csr<<<nchunks * NSEG, 256, 0, stream>>>(src, packed, row_ptr, col, ne, NSEG, seg_size);

  int gemm_blocks = (n + 63) / 64;
  int agg_blocks = (n + 3) / 4;  // 4 waves/block, 1 wave/node

  gemm_scale_h<<<gemm_blocks, 256, 0, stream>>>(x, W1, dinv, hsh, n);
  aggregate_h<<<agg_blocks, 256, 0, stream>>>(hsh, row_ptr, col, dinv, b1, h1, n);
  gemm_scale_h<<<gemm_blocks, 256, 0, stream>>>(h1, W2, dinv, hsh, n);  // reuse hsh
  aggregate_dot_h<<<agg_blocks, 256, 0, stream>>>(hsh, row_ptr, col, dinv, b2, Wc, bc, out, n);
}